// Round 8
// baseline (223.402 us; speedup 1.0000x reference)
//
#include <hip/hip_runtime.h>

// ---- types ----
typedef __bf16        bf16x8 __attribute__((ext_vector_type(8)));
typedef float         f32x4  __attribute__((ext_vector_type(4)));
typedef unsigned short u16x4 __attribute__((ext_vector_type(4)));
typedef unsigned short u16x8 __attribute__((ext_vector_type(8)));
typedef unsigned int  u32x4  __attribute__((ext_vector_type(4)));

#define MFMA16(a,b,c) __builtin_amdgcn_mfma_f32_16x16x32_bf16((a),(b),(c),0,0,0)

static __device__ __forceinline__ unsigned short f2bf(float f) {
  unsigned int u = __builtin_bit_cast(unsigned int, f);
  u += 0x7fffu + ((u >> 16) & 1u);          // RNE; inputs are finite
  return (unsigned short)(u >> 16);
}
static __device__ __forceinline__ unsigned int pk2rne(float a, float b) {
  return (unsigned int)f2bf(a) | ((unsigned int)f2bf(b) << 16);
}
// packed f32x2 -> bf16x2: 1 inst on gfx950, guarded fallback otherwise
static __device__ __forceinline__ unsigned int pkrn(float a, float b) {
#if __has_builtin(__builtin_amdgcn_cvt_pk_bf16_f32)
  auto r = __builtin_amdgcn_cvt_pk_bf16_f32(a, b);   // src0 -> low half
  return __builtin_bit_cast(unsigned int, r);
#else
  return pk2rne(a, b);
#endif
}
static __device__ __forceinline__ bf16x8 as_bf(u32x4 v) {
  return __builtin_bit_cast(bf16x8, v);
}
static __device__ __forceinline__ float bf2f(unsigned short u) {
  return __builtin_bit_cast(float, ((unsigned int)u) << 16);
}

// Problem constants
#define SDIM 4096
#define CDIM 256
#define NHEAD 4
#define HDIM 64
#define NBATCH 2
#define KSPLIT 4

// ---------------------------------------------------------------------------
// 1) merged prep: blocks 0..255 = GN partial stats; 256..319 = weight cast to
//    FRAG-LINEAR bf16:  Wf[(ot*8+kc)*64 + lane]*8 = W[ot*16+(l&15)][kc*32+(l>>4)*8 ..+8)
__global__ __launch_bounds__(256) void k_prep(const float* __restrict__ x,
                                              const float* __restrict__ wq,
                                              const float* __restrict__ wo,
                                              unsigned short* __restrict__ wqf,
                                              unsigned short* __restrict__ wof,
                                              float2* __restrict__ Sp) {
  int j = blockIdx.x, i = threadIdx.x;
  if (j < 256) {
    const float* p = x + (size_t)(j >> 3) * 65536 + (size_t)(j & 7) * 8192;
    float s = 0.f, sq = 0.f;
#pragma unroll
    for (int r = 0; r < 8; ++r) {
      float4 v = *(const float4*)(p + (r * 256 + i) * 4);
      s  += v.x + v.y + v.z + v.w;
      sq += v.x * v.x + v.y * v.y + v.z * v.z + v.w * v.w;
    }
    __shared__ float rs[256], rq[256];
    rs[i] = s; rq[i] = sq;
    __syncthreads();
    for (int off = 128; off > 0; off >>= 1) {
      if (i < off) { rs[i] += rs[i + off]; rq[i] += rq[i + off]; }
      __syncthreads();
    }
    if (i == 0) Sp[j] = make_float2(rs[0], rq[0]);
  } else {
    int t = (j - 256) * 256 + i;          // 2 frag-rows each
#pragma unroll
    for (int u = 0; u < 2; ++u) {
      int G = t * 2 + u;                  // 0..32767 = 24576 (wq) + 8192 (wo)
      const float* src; unsigned short* dst;
      if (G < 24576) {
        int tile = G >> 6, l = G & 63;
        src = wq + (size_t)((tile >> 3) * 16 + (l & 15)) * 256 + (tile & 7) * 32 + (l >> 4) * 8;
        dst = wqf + (size_t)G * 8;
      } else {
        int G2 = G - 24576, tile = G2 >> 6, l = G2 & 63;
        src = wo + (size_t)((tile >> 3) * 16 + (l & 15)) * 256 + (tile & 7) * 32 + (l >> 4) * 8;
        dst = wof + (size_t)G2 * 8;
      }
      float4 v0 = *(const float4*)src, v1 = *(const float4*)(src + 4);
      u16x8 r;
      r[0] = f2bf(v0.x); r[1] = f2bf(v0.y); r[2] = f2bf(v0.z); r[3] = f2bf(v0.w);
      r[4] = f2bf(v1.x); r[5] = f2bf(v1.y); r[6] = f2bf(v1.z); r[7] = f2bf(v1.w);
      *(u16x8*)dst = r;
    }
  }
}

// ---------------------------------------------------------------------------
// 2) GN apply + transpose: x[b][c][s] fp32 -> Xf frag-linear bf16
__global__ __launch_bounds__(256) void k_gn_apply(const float* __restrict__ x,
                                                  const float2* __restrict__ Sp,
                                                  const float* __restrict__ gnw,
                                                  const float* __restrict__ gnb,
                                                  unsigned short* __restrict__ Xf) {
  __shared__ __attribute__((aligned(16))) unsigned short sT[64 * 268];
  __shared__ float2 sStat[16];
  int b = blockIdx.y, s0 = blockIdx.x * 64;
  int i = threadIdx.x, lane = i & 63, w = i >> 6;
  if (i < 16) {
    float s = 0.f, sq = 0.f;
#pragma unroll
    for (int u = 0; u < 8; ++u) {
      float2 v = Sp[(b * 16 + i) * 8 + u];
      s += v.x; sq += v.y;
    }
    float mean = s * (1.f / 65536.f);
    float var  = sq * (1.f / 65536.f) - mean * mean;
    sStat[i] = make_float2(mean, rsqrtf(var + 1e-5f));
  }
  __syncthreads();
#pragma unroll 4
  for (int r = 0; r < 64; ++r) {
    int c = r * 4 + w;
    float v = x[((size_t)(b * CDIM + c)) * SDIM + s0 + lane];
    float2 st = sStat[c >> 4];
    float nv = (v - st.x) * st.y * gnw[c] + gnb[c];
    sT[lane * 268 + c] = f2bf(nv);
  }
  __syncthreads();
  int l = i & 63, fr = i >> 6;
#pragma unroll
  for (int g = 0; g < 8; ++g) {
    int tile = fr * 8 + g, st = tile >> 3, kc = tile & 7;
    const unsigned short* src = &sT[(st * 16 + (l & 15)) * 268 + kc * 32 + (l >> 4) * 8];
    u16x4 lo = *(const u16x4*)src, hi = *(const u16x4*)(src + 4);
    unsigned short* dst = Xf + (((size_t)(b * 256 + (s0 >> 4) + st) * 8 + kc) * 64 + l) * 8;
    *(u16x4*)dst = lo;
    *(u16x4*)(dst + 4) = hi;
  }
}

// ---------------------------------------------------------------------------
// 3) QKV GEMM (barrier-free, frag-linear operands), epilogue repacks into:
//    Qf/Kf[bh][t16=s/16][ks=d/32][lane][8]  (Q pre-scaled by log2(e)/16)
//    Vf[bh][t32=s/32][dt=d/16][lane][8]
__global__ __launch_bounds__(256) void k_qkv(const unsigned short* __restrict__ Wf,
                                             const unsigned short* __restrict__ Xf,
                                             unsigned short* __restrict__ Qf,
                                             unsigned short* __restrict__ Kf,
                                             unsigned short* __restrict__ Vf) {
  __shared__ __attribute__((aligned(16))) unsigned short sB[64 * 68];  // epilogue bounce
  int b = blockIdx.z, s0 = blockIdx.y * 64, o0 = blockIdx.x * 64;
  int i = threadIdx.x, lane = i & 63, w = i >> 6;
  int quad = lane >> 4, m = lane & 15;
  int ot = blockIdx.x * 4 + w;
  int stg = s0 >> 4;

  f32x4 acc[4] = {};
#pragma unroll
  for (int kc = 0; kc < 8; ++kc) {
    bf16x8 aW = as_bf(*(const u32x4*)(Wf + (((size_t)ot * 8 + kc) * 64 + lane) * 8));
#pragma unroll
    for (int st = 0; st < 4; ++st) {
      bf16x8 bX = as_bf(*(const u32x4*)(Xf + ((((size_t)b * 256 + stg + st) * 8 + kc) * 64 + lane) * 8));
      acc[st] = MFMA16(aW, bX, acc[st]);
    }
  }

  int sec = (o0 >> 6) % 3;             // 0=Q, 1=K, 2=V
  int h   = o0 / 192;
  int bh  = b * NHEAD + h;
  float qs = (sec == 0) ? 0.09016844f : 1.0f;   // log2(e)/16 folded into Q
#pragma unroll
  for (int st = 0; st < 4; ++st) {
    uint2 pk = make_uint2(pk2rne(acc[st][0] * qs, acc[st][1] * qs),
                          pk2rne(acc[st][2] * qs, acc[st][3] * qs));
    *(uint2*)&sB[(st * 16 + m) * 68 + w * 16 + quad * 4] = pk;
  }
  __syncthreads();
  int lp = i & 63, qp = lp >> 4, mp = lp & 15, t = i >> 6;
  if (sec < 2) {
    unsigned short* base = (sec == 0) ? Qf : Kf;
#pragma unroll
    for (int ks = 0; ks < 2; ++ks) {
      const unsigned short* src = &sB[(t * 16 + mp) * 68 + ks * 32 + qp * 8];
      u16x4 lo = *(const u16x4*)src;
      u16x4 hi = *(const u16x4*)(src + 4);
      unsigned short* dst = base + ((((size_t)bh * 256 + (s0 >> 4) + t) * 2 + ks) * 64 + lp) * 8;
      *(u16x4*)dst = lo;
      *(u16x4*)(dst + 4) = hi;
    }
  } else {
    int kt32l = t >> 1, dts = (t & 1) * 2;
#pragma unroll
    for (int dd = 0; dd < 2; ++dd) {
      int dt = dts + dd;
      u16x8 v;
#pragma unroll
      for (int jj = 0; jj < 8; ++jj)
        v[jj] = sB[(kt32l * 32 + qp * 8 + jj) * 68 + dt * 16 + mp];
      unsigned short* dst = Vf + ((((size_t)bh * 128 + (s0 >> 5) + kt32l) * 4 + dt) * 64 + lp) * 8;
      *(u16x8*)dst = v;
    }
  }
}

// ---------------------------------------------------------------------------
// 4) Flash attention v5: barrier-free + K-PREFETCH software pipeline.
//    Unroll-by-2: K frags for it+1 are issued BEFORE body(it) so the
//    load-to-use distance is a full body (~400 cyc) instead of ~0 (the R7
//    stall). V loads stay in-body (use is ~200 cyc later, behind QK+softmax).
//    li via VALU tree (not MFMA) to keep VGPR+AGPR <= 128 for 4 waves/SIMD.
//    Partials: Opb bf16 [ks][bh][q][64], Lp fp32 [ks][bh][q].
__global__ __launch_bounds__(256, 4) void k_attn(const unsigned short* __restrict__ Qf,
                                                 const unsigned short* __restrict__ Kf,
                                                 const unsigned short* __restrict__ Vf,
                                                 unsigned short* __restrict__ Opb,
                                                 float* __restrict__ Lp) {
  __shared__ __attribute__((aligned(16))) unsigned short sP[4][32 * 40];
  int bh = blockIdx.y, kk = blockIdx.z;
  int i = threadIdx.x, lane = i & 63, w = i >> 6;
  int quad = lane >> 4, m = lane & 15;
  constexpr int ITERS = SDIM / KSPLIT / 32;   // 32

  // Q B-frags: wave w owns q-tiles {blockIdx.x*8 + w*2, +1}
  bf16x8 bq[2][2];
#pragma unroll
  for (int qt = 0; qt < 2; ++qt)
#pragma unroll
    for (int ks = 0; ks < 2; ++ks)
      bq[qt][ks] = as_bf(*(const u32x4*)(Qf +
        ((((size_t)bh * 256 + (blockIdx.x * 8 + w * 2 + qt)) * 2 + ks) * 64 + lane) * 8));

  f32x4 oacc[2][4] = {};
  float li[2] = {0.f, 0.f};

  bf16x8 akb[2][2][2];   // [parity][ky][ks] K-frag double buffer

  auto loadK = [&](int it, int par) {
    int kb16 = kk * (ITERS * 2) + it * 2;
#pragma unroll
    for (int ky = 0; ky < 2; ++ky)
#pragma unroll
      for (int ks = 0; ks < 2; ++ks)
        akb[par][ky][ks] = as_bf(*(const u32x4*)(Kf +
          ((((size_t)bh * 256 + kb16 + ky) * 2 + ks) * 64 + lane) * 8));
  };

  auto body = [&](int it, int par) {
    // V frags (use is late in the body -> latency mostly hidden)
    bf16x8 av[4];
    int kb32 = kk * ITERS + it;
#pragma unroll
    for (int dt = 0; dt < 4; ++dt)
      av[dt] = as_bf(*(const u32x4*)(Vf +
        ((((size_t)bh * 128 + kb32) * 4 + dt) * 64 + lane) * 8));

#pragma unroll
    for (int qt = 0; qt < 2; ++qt) {
      f32x4 sc0 = {-18.f, -18.f, -18.f, -18.f};   // fixed-max shift in C-init
      f32x4 sc1 = sc0;
      sc0 = MFMA16(akb[par][0][0], bq[qt][0], sc0);
      sc0 = MFMA16(akb[par][0][1], bq[qt][1], sc0);
      sc1 = MFMA16(akb[par][1][0], bq[qt][0], sc1);
      sc1 = MFMA16(akb[par][1][1], bq[qt][1], sc1);
      float p[8];
#pragma unroll
      for (int r = 0; r < 4; ++r) {
        p[r]     = __builtin_amdgcn_exp2f(sc0[r]);
        p[4 + r] = __builtin_amdgcn_exp2f(sc1[r]);
      }
      li[qt] += ((p[0] + p[1]) + (p[2] + p[3])) + ((p[4] + p[5]) + (p[6] + p[7]));
      int row = (qt * 16 + m) * 40;
      *(uint2*)&sP[w][row + quad * 4]      = make_uint2(pkrn(p[0], p[1]), pkrn(p[2], p[3]));
      *(uint2*)&sP[w][row + 16 + quad * 4] = make_uint2(pkrn(p[4], p[5]), pkrn(p[6], p[7]));
    }
#pragma unroll
    for (int qt = 0; qt < 2; ++qt) {
      bf16x8 bp = *(const bf16x8*)&sP[w][(qt * 16 + m) * 40 + quad * 8];
#pragma unroll
      for (int dt = 0; dt < 4; ++dt)
        oacc[qt][dt] = MFMA16(av[dt], bp, oacc[qt][dt]);
    }
  };

  loadK(0, 0);
  for (int it = 0; it < ITERS; it += 2) {
    loadK(it + 1, 1);                 // prefetch: full body ahead of use
    body(it, 0);
    if (it + 2 < ITERS) loadK(it + 2, 0);
    body(it + 1, 1);
  }

  // epilogue: quads hold disjoint key subsets -> reduce li, store partials
  size_t qg = (size_t)(kk * 8 + bh) * SDIM + blockIdx.x * 128 + w * 32;
#pragma unroll
  for (int qt = 0; qt < 2; ++qt) {
    li[qt] += __shfl_xor(li[qt], 16);
    li[qt] += __shfl_xor(li[qt], 32);
  }
  if (quad == 0) {
#pragma unroll
    for (int qt = 0; qt < 2; ++qt) Lp[qg + qt * 16 + m] = li[qt];
  }
#pragma unroll
  for (int qt = 0; qt < 2; ++qt)
#pragma unroll
    for (int dt = 0; dt < 4; ++dt) {
      uint2 pk = make_uint2(pk2rne(oacc[qt][dt][0], oacc[qt][dt][1]),
                            pk2rne(oacc[qt][dt][2], oacc[qt][dt][3]));
      *(uint2*)&Opb[(qg + qt * 16 + m) * 64 + dt * 16 + quad * 4] = pk;
    }
}

// ---------------------------------------------------------------------------
// 5) FUSED combine + proj GEMM + bias + residual.
//    D[o][s] = sum_h inv_li[h][s] * sum_{c in h} W[o][c] * (sum_kk Opb_kk[s][c])
//    Per-head fp32 accumulators (4h x 4st = 64 AGPR); kk-sum folded into the
//    MFMA accumulation (strictly more accurate than the old bf16 combine).
__global__ __launch_bounds__(256) void k_proj(const unsigned short* __restrict__ Wf,
                                              const unsigned short* __restrict__ Opb,
                                              const float* __restrict__ Lp,
                                              const float* __restrict__ bias,
                                              const float* __restrict__ resid,
                                              float* __restrict__ out) {
  int b = blockIdx.z, s0 = blockIdx.y * 64, o0 = blockIdx.x * 64;
  int i = threadIdx.x, lane = i & 63, w = i >> 6;
  int quad = lane >> 4, m = lane & 15;
  int ot = blockIdx.x * 4 + w;

  f32x4 acc[4][4] = {};   // [h][st]
#pragma unroll
  for (int kc = 0; kc < 8; ++kc) {
    bf16x8 aW = as_bf(*(const u32x4*)(Wf + (((size_t)ot * 8 + kc) * 64 + lane) * 8));
    int h = kc >> 1;
#pragma unroll
    for (int kkq = 0; kkq < KSPLIT; ++kkq) {
#pragma unroll
      for (int st = 0; st < 4; ++st) {
        const unsigned short* p = Opb +
          ((size_t)(kkq * 8 + b * NHEAD + h) * SDIM + s0 + st * 16 + m) * 64 +
          (kc & 1) * 32 + quad * 8;
        bf16x8 bX = as_bf(*(const u32x4*)p);
        acc[h][st] = MFMA16(aW, bX, acc[h][st]);
      }
    }
  }

  // per-(h, s) normalizers
  float inv[4][4];
#pragma unroll
  for (int h = 0; h < 4; ++h)
#pragma unroll
    for (int st = 0; st < 4; ++st) {
      size_t base = (size_t)(b * NHEAD + h) * SDIM + s0 + st * 16 + m;
      float l = Lp[base] + Lp[base + 8ull * SDIM] + Lp[base + 16ull * SDIM] + Lp[base + 24ull * SDIM];
      inv[h][st] = 1.f / l;
    }

#pragma unroll
  for (int st = 0; st < 4; ++st)
#pragma unroll
    for (int r = 0; r < 4; ++r) {
      int o = o0 + w * 16 + quad * 4 + r;
      int s = s0 + st * 16 + m;
      float v = acc[0][st][r] * inv[0][st] + acc[1][st][r] * inv[1][st] +
                acc[2][st][r] * inv[2][st] + acc[3][st][r] * inv[3][st];
      size_t idx = ((size_t)b * CDIM + o) * SDIM + s;
      out[idx] = v + bias[o] + resid[idx];
    }
}

// ---------------------------------------------------------------------------
extern "C" void kernel_launch(void* const* d_in, const int* in_sizes, int n_in,
                              void* d_out, int out_size, void* d_ws, size_t ws_size,
                              hipStream_t stream) {
  const float* input = (const float*)d_in[0];
  const float* gnw   = (const float*)d_in[1];
  const float* gnb   = (const float*)d_in[2];
  const float* wq    = (const float*)d_in[3];
  const float* wo    = (const float*)d_in[4];
  const float* ob    = (const float*)d_in[5];
  float* out = (float*)d_out;

  char* ws = (char*)d_ws;
  unsigned short* Xf  = (unsigned short*)(ws);                        // 4 MB frag-linear GN(x)
  unsigned short* Qf  = (unsigned short*)(ws + (4ull  << 20));        // 4 MB
  unsigned short* Kf  = (unsigned short*)(ws + (8ull  << 20));        // 4 MB
  unsigned short* Vf  = (unsigned short*)(ws + (12ull << 20));        // 4 MB
  unsigned short* wqf = (unsigned short*)(ws + (20ull << 20));        // 384 KB frag-linear
  unsigned short* wof = (unsigned short*)(ws + (20ull << 20) + (1u << 19)); // 128 KB
  float2* Sp          = (float2*)(ws + (20ull << 20) + (3u << 18));   // 2 KB
  float* Lp           = (float*)(ws + (21ull << 20));                 // 512 KB
  unsigned short* Opb = (unsigned short*)(ws + (22ull << 20));        // 16 MB

  k_prep<<<320, 256, 0, stream>>>(input, wq, wo, wqf, wof, Sp);
  k_gn_apply<<<dim3(64, NBATCH), 256, 0, stream>>>(input, Sp, gnw, gnb, Xf);
  k_qkv<<<dim3(12, 64, NBATCH), 256, 0, stream>>>(wqf, Xf, Qf, Kf, Vf);
  k_attn<<<dim3(32, NHEAD * NBATCH, KSPLIT), 256, 0, stream>>>(Qf, Kf, Vf, Opb, Lp);
  k_proj<<<dim3(4, 64, NBATCH), 256, 0, stream>>>(wof, Opb, Lp, ob, input, out);
}

// Round 9
// 175.570 us; speedup vs baseline: 1.2724x; 1.2724x over previous
//
#include <hip/hip_runtime.h>

// ---- types ----
typedef __bf16        bf16x8 __attribute__((ext_vector_type(8)));
typedef float         f32x4  __attribute__((ext_vector_type(4)));
typedef unsigned short u16x4 __attribute__((ext_vector_type(4)));
typedef unsigned short u16x8 __attribute__((ext_vector_type(8)));
typedef unsigned int  u32x4  __attribute__((ext_vector_type(4)));

#define MFMA16(a,b,c) __builtin_amdgcn_mfma_f32_16x16x32_bf16((a),(b),(c),0,0,0)

static __device__ __forceinline__ unsigned short f2bf(float f) {
  unsigned int u = __builtin_bit_cast(unsigned int, f);
  u += 0x7fffu + ((u >> 16) & 1u);          // RNE; inputs are finite
  return (unsigned short)(u >> 16);
}
static __device__ __forceinline__ unsigned int pk2rne(float a, float b) {
  return (unsigned int)f2bf(a) | ((unsigned int)f2bf(b) << 16);
}
// packed f32x2 -> bf16x2: 1 inst on gfx950, guarded fallback otherwise
static __device__ __forceinline__ unsigned int pkrn(float a, float b) {
#if __has_builtin(__builtin_amdgcn_cvt_pk_bf16_f32)
  auto r = __builtin_amdgcn_cvt_pk_bf16_f32(a, b);   // src0 -> low half
  return __builtin_bit_cast(unsigned int, r);
#else
  return pk2rne(a, b);
#endif
}
static __device__ __forceinline__ bf16x8 as_bf(u32x4 v) {
  return __builtin_bit_cast(bf16x8, v);
}

// Problem constants
#define SDIM 4096
#define CDIM 256
#define NHEAD 4
#define HDIM 64
#define NBATCH 2

// ---------------------------------------------------------------------------
// 1) merged prep: blocks 0..255 = GN partial stats; 256..319 = weight cast to
//    FRAG-LINEAR bf16:  Wf[(ot*8+kc)*64 + lane]*8 = W[ot*16+(l&15)][kc*32+(l>>4)*8 ..+8)
__global__ __launch_bounds__(256) void k_prep(const float* __restrict__ x,
                                              const float* __restrict__ wq,
                                              const float* __restrict__ wo,
                                              unsigned short* __restrict__ wqf,
                                              unsigned short* __restrict__ wof,
                                              float2* __restrict__ Sp) {
  int j = blockIdx.x, i = threadIdx.x;
  if (j < 256) {
    const float* p = x + (size_t)(j >> 3) * 65536 + (size_t)(j & 7) * 8192;
    float s = 0.f, sq = 0.f;
#pragma unroll
    for (int r = 0; r < 8; ++r) {
      float4 v = *(const float4*)(p + (r * 256 + i) * 4);
      s  += v.x + v.y + v.z + v.w;
      sq += v.x * v.x + v.y * v.y + v.z * v.z + v.w * v.w;
    }
    __shared__ float rs[256], rq[256];
    rs[i] = s; rq[i] = sq;
    __syncthreads();
    for (int off = 128; off > 0; off >>= 1) {
      if (i < off) { rs[i] += rs[i + off]; rq[i] += rq[i + off]; }
      __syncthreads();
    }
    if (i == 0) Sp[j] = make_float2(rs[0], rq[0]);
  } else {
    int t = (j - 256) * 256 + i;          // 2 frag-rows each
#pragma unroll
    for (int u = 0; u < 2; ++u) {
      int G = t * 2 + u;                  // 0..32767 = 24576 (wq) + 8192 (wo)
      const float* src; unsigned short* dst;
      if (G < 24576) {
        int tile = G >> 6, l = G & 63;
        src = wq + (size_t)((tile >> 3) * 16 + (l & 15)) * 256 + (tile & 7) * 32 + (l >> 4) * 8;
        dst = wqf + (size_t)G * 8;
      } else {
        int G2 = G - 24576, tile = G2 >> 6, l = G2 & 63;
        src = wo + (size_t)((tile >> 3) * 16 + (l & 15)) * 256 + (tile & 7) * 32 + (l >> 4) * 8;
        dst = wof + (size_t)G2 * 8;
      }
      float4 v0 = *(const float4*)src, v1 = *(const float4*)(src + 4);
      u16x8 r;
      r[0] = f2bf(v0.x); r[1] = f2bf(v0.y); r[2] = f2bf(v0.z); r[3] = f2bf(v0.w);
      r[4] = f2bf(v1.x); r[5] = f2bf(v1.y); r[6] = f2bf(v1.z); r[7] = f2bf(v1.w);
      *(u16x8*)dst = r;
    }
  }
}

// ---------------------------------------------------------------------------
// 2) GN apply + transpose: x[b][c][s] fp32 -> Xf frag-linear bf16
__global__ __launch_bounds__(256) void k_gn_apply(const float* __restrict__ x,
                                                  const float2* __restrict__ Sp,
                                                  const float* __restrict__ gnw,
                                                  const float* __restrict__ gnb,
                                                  unsigned short* __restrict__ Xf) {
  __shared__ __attribute__((aligned(16))) unsigned short sT[64 * 268];
  __shared__ float2 sStat[16];
  int b = blockIdx.y, s0 = blockIdx.x * 64;
  int i = threadIdx.x, lane = i & 63, w = i >> 6;
  if (i < 16) {
    float s = 0.f, sq = 0.f;
#pragma unroll
    for (int u = 0; u < 8; ++u) {
      float2 v = Sp[(b * 16 + i) * 8 + u];
      s += v.x; sq += v.y;
    }
    float mean = s * (1.f / 65536.f);
    float var  = sq * (1.f / 65536.f) - mean * mean;
    sStat[i] = make_float2(mean, rsqrtf(var + 1e-5f));
  }
  __syncthreads();
#pragma unroll 4
  for (int r = 0; r < 64; ++r) {
    int c = r * 4 + w;
    float v = x[((size_t)(b * CDIM + c)) * SDIM + s0 + lane];
    float2 st = sStat[c >> 4];
    float nv = (v - st.x) * st.y * gnw[c] + gnb[c];
    sT[lane * 268 + c] = f2bf(nv);
  }
  __syncthreads();
  int l = i & 63, fr = i >> 6;
#pragma unroll
  for (int g = 0; g < 8; ++g) {
    int tile = fr * 8 + g, st = tile >> 3, kc = tile & 7;
    const unsigned short* src = &sT[(st * 16 + (l & 15)) * 268 + kc * 32 + (l >> 4) * 8];
    u16x4 lo = *(const u16x4*)src, hi = *(const u16x4*)(src + 4);
    unsigned short* dst = Xf + (((size_t)(b * 256 + (s0 >> 4) + st) * 8 + kc) * 64 + l) * 8;
    *(u16x4*)dst = lo;
    *(u16x4*)(dst + 4) = hi;
  }
}

// ---------------------------------------------------------------------------
// 3) QKV GEMM (barrier-free K-loop, frag-linear operands), epilogue repacks:
//    Qf/Kf[bh][t16=s/16][ks=d/32][lane][8]  (Q pre-scaled by log2(e)/16)
//    Vf[bh][t32=s/32][dt=d/16][lane][8]
__global__ __launch_bounds__(256) void k_qkv(const unsigned short* __restrict__ Wf,
                                             const unsigned short* __restrict__ Xf,
                                             unsigned short* __restrict__ Qf,
                                             unsigned short* __restrict__ Kf,
                                             unsigned short* __restrict__ Vf) {
  __shared__ __attribute__((aligned(16))) unsigned short sB[64 * 68];  // epilogue bounce
  int b = blockIdx.z, s0 = blockIdx.y * 64, o0 = blockIdx.x * 64;
  int i = threadIdx.x, lane = i & 63, w = i >> 6;
  int quad = lane >> 4, m = lane & 15;
  int ot = blockIdx.x * 4 + w;
  int stg = s0 >> 4;

  f32x4 acc[4] = {};
#pragma unroll
  for (int kc = 0; kc < 8; ++kc) {
    bf16x8 aW = as_bf(*(const u32x4*)(Wf + (((size_t)ot * 8 + kc) * 64 + lane) * 8));
#pragma unroll
    for (int st = 0; st < 4; ++st) {
      bf16x8 bX = as_bf(*(const u32x4*)(Xf + ((((size_t)b * 256 + stg + st) * 8 + kc) * 64 + lane) * 8));
      acc[st] = MFMA16(aW, bX, acc[st]);
    }
  }

  int sec = (o0 >> 6) % 3;             // 0=Q, 1=K, 2=V
  int h   = o0 / 192;
  int bh  = b * NHEAD + h;
  float qs = (sec == 0) ? 0.09016844f : 1.0f;   // log2(e)/16 folded into Q
#pragma unroll
  for (int st = 0; st < 4; ++st) {
    uint2 pk = make_uint2(pk2rne(acc[st][0] * qs, acc[st][1] * qs),
                          pk2rne(acc[st][2] * qs, acc[st][3] * qs));
    *(uint2*)&sB[(st * 16 + m) * 68 + w * 16 + quad * 4] = pk;
  }
  __syncthreads();
  int lp = i & 63, qp = lp >> 4, mp = lp & 15, t = i >> 6;
  if (sec < 2) {
    unsigned short* base = (sec == 0) ? Qf : Kf;
#pragma unroll
    for (int ks = 0; ks < 2; ++ks) {
      const unsigned short* src = &sB[(t * 16 + mp) * 68 + ks * 32 + qp * 8];
      u16x4 lo = *(const u16x4*)src;
      u16x4 hi = *(const u16x4*)(src + 4);
      unsigned short* dst = base + ((((size_t)bh * 256 + (s0 >> 4) + t) * 2 + ks) * 64 + lp) * 8;
      *(u16x4*)dst = lo;
      *(u16x4*)(dst + 4) = hi;
    }
  } else {
    int kt32l = t >> 1, dts = (t & 1) * 2;
#pragma unroll
    for (int dd = 0; dd < 2; ++dd) {
      int dt = dts + dd;
      u16x8 v;
#pragma unroll
      for (int jj = 0; jj < 8; ++jj)
        v[jj] = sB[(kt32l * 32 + qp * 8 + jj) * 68 + dt * 16 + mp];
      unsigned short* dst = Vf + ((((size_t)bh * 128 + (s0 >> 5) + kt32l) * 4 + dt) * 64 + lp) * 8;
      *(u16x8*)dst = v;
    }
  }
}

// ---------------------------------------------------------------------------
// 4) Flash attention v6: exact R7 body (no prefetch — R8's akb dbuf spilled),
//    KSPLIT=KS with small LDS so 8 blocks/CU can be resident (32 waves/CU).
//    Epilogue bounces O through LDS to write Opb in PROJ-B-FRAG-LINEAR layout
//    Opb[kkbh][t16=q/16][kc=d/32][lane][8] (same shape as Qf) -> the fused
//    proj reads it fully coalesced. Lp fp32 [kkbh][q].
template <int KS>
__global__ __launch_bounds__(256, 4) void k_attn(const unsigned short* __restrict__ Qf,
                                                 const unsigned short* __restrict__ Kf,
                                                 const unsigned short* __restrict__ Vf,
                                                 unsigned short* __restrict__ Opb,
                                                 float* __restrict__ Lp) {
  // union: main loop uses sP (4 waves x 32q x 40 = 10240 B);
  // epilogue reuses as obuf bf16 [128 q][72] = 18432 B
  __shared__ __attribute__((aligned(16))) unsigned short smem[128 * 72];
  int bh = blockIdx.y, kk = blockIdx.z;
  int i = threadIdx.x, lane = i & 63, w = i >> 6;
  int quad = lane >> 4, m = lane & 15;
  constexpr int ITERS = SDIM / KS / 32;
  unsigned short* sP = smem + w * 1280;   // per-wave [32q][40]

  // Q B-frags: wave w owns q-tiles {blockIdx.x*8 + w*2, +1}
  bf16x8 bq[2][2];
#pragma unroll
  for (int qt = 0; qt < 2; ++qt)
#pragma unroll
    for (int ks = 0; ks < 2; ++ks)
      bq[qt][ks] = as_bf(*(const u32x4*)(Qf +
        ((((size_t)bh * 256 + (blockIdx.x * 8 + w * 2 + qt)) * 2 + ks) * 64 + lane) * 8));

  f32x4 oacc[2][4] = {};
  float li[2] = {0.f, 0.f};

  for (int it = 0; it < ITERS; ++it) {
    // V frags first (use is late in the body -> latency mostly hidden)
    bf16x8 av[4];
    int kb32 = kk * ITERS + it;
#pragma unroll
    for (int dt = 0; dt < 4; ++dt)
      av[dt] = as_bf(*(const u32x4*)(Vf +
        ((((size_t)bh * 128 + kb32) * 4 + dt) * 64 + lane) * 8));

    bf16x8 ak[2][2];
    int kb16 = kk * (ITERS * 2) + it * 2;
#pragma unroll
    for (int ky = 0; ky < 2; ++ky)
#pragma unroll
      for (int ks = 0; ks < 2; ++ks)
        ak[ky][ks] = as_bf(*(const u32x4*)(Kf +
          ((((size_t)bh * 256 + kb16 + ky) * 2 + ks) * 64 + lane) * 8));

#pragma unroll
    for (int qt = 0; qt < 2; ++qt) {
      f32x4 sc0 = {-18.f, -18.f, -18.f, -18.f};   // fixed-max shift in C-init
      f32x4 sc1 = sc0;
      sc0 = MFMA16(ak[0][0], bq[qt][0], sc0);
      sc0 = MFMA16(ak[0][1], bq[qt][1], sc0);
      sc1 = MFMA16(ak[1][0], bq[qt][0], sc1);
      sc1 = MFMA16(ak[1][1], bq[qt][1], sc1);
      float p[8];
#pragma unroll
      for (int r = 0; r < 4; ++r) {
        p[r]     = __builtin_amdgcn_exp2f(sc0[r]);
        p[4 + r] = __builtin_amdgcn_exp2f(sc1[r]);
      }
      li[qt] += ((p[0] + p[1]) + (p[2] + p[3])) + ((p[4] + p[5]) + (p[6] + p[7]));
      int row = (qt * 16 + m) * 40;
      *(uint2*)&sP[row + quad * 4]      = make_uint2(pkrn(p[0], p[1]), pkrn(p[2], p[3]));
      *(uint2*)&sP[row + 16 + quad * 4] = make_uint2(pkrn(p[4], p[5]), pkrn(p[6], p[7]));
    }
#pragma unroll
    for (int qt = 0; qt < 2; ++qt) {
      bf16x8 bp = *(const bf16x8*)&sP[(qt * 16 + m) * 40 + quad * 8];
#pragma unroll
      for (int dt = 0; dt < 4; ++dt)
        oacc[qt][dt] = MFMA16(av[dt], bp, oacc[qt][dt]);
    }
  }

  // li: quads hold disjoint key subsets -> reduce, store
  size_t lg = (size_t)(kk * 8 + bh) * SDIM + blockIdx.x * 128 + w * 32;
#pragma unroll
  for (int qt = 0; qt < 2; ++qt) {
    li[qt] += __shfl_xor(li[qt], 16);
    li[qt] += __shfl_xor(li[qt], 32);
  }
  if (quad == 0) {
#pragma unroll
    for (int qt = 0; qt < 2; ++qt) Lp[lg + qt * 16 + m] = li[qt];
  }

  // O: bounce through LDS into proj-B-frag-linear Opb
  __syncthreads();   // all waves done with sP
  unsigned short* ob = smem;   // [128 q][72]
#pragma unroll
  for (int qt = 0; qt < 2; ++qt)
#pragma unroll
    for (int dt = 0; dt < 4; ++dt) {
      int ql = w * 32 + qt * 16 + m, d0 = dt * 16 + quad * 4;
      *(unsigned int*)&ob[ql * 72 + d0]     = pkrn(oacc[qt][dt][0], oacc[qt][dt][1]);
      *(unsigned int*)&ob[ql * 72 + d0 + 2] = pkrn(oacc[qt][dt][2], oacc[qt][dt][3]);
    }
  __syncthreads();
  int l = i & 63, sub = i >> 6, mp = l & 15, qp = l >> 4;
#pragma unroll
  for (int tt = 0; tt < 2; ++tt)
#pragma unroll
    for (int kc = 0; kc < 2; ++kc) {
      int t16l = sub * 2 + tt;
      u16x8 v = *(const u16x8*)&ob[(t16l * 16 + mp) * 72 + kc * 32 + qp * 8];
      size_t idx = ((((size_t)(kk * 8 + bh) * 256 + blockIdx.x * 8 + t16l) * 2 + kc) * 64 + l) * 8;
      *(u16x8*)(Opb + idx) = v;
    }
}

// ---------------------------------------------------------------------------
// 5) FUSED combine + proj GEMM + bias + residual (coalesced Opb reads).
//    D[o][s] = sum_h inv_l[h][s] * sum_{c in h, kk} W[o][c] * Opb_kk[s][c]
//    s-tile 32 -> acc[4][2] = 32 AGPR, ~92 regs total -> 4 waves/SIMD safe.
template <int KS>
__global__ __launch_bounds__(256, 4) void k_proj(const unsigned short* __restrict__ Wf,
                                                 const unsigned short* __restrict__ Opb,
                                                 const float* __restrict__ Lp,
                                                 const float* __restrict__ bias,
                                                 const float* __restrict__ resid,
                                                 float* __restrict__ out) {
  int b = blockIdx.z, s0 = blockIdx.y * 32, o0 = blockIdx.x * 64;
  int i = threadIdx.x, lane = i & 63, w = i >> 6;
  int quad = lane >> 4, m = lane & 15;
  int ot = blockIdx.x * 4 + w;
  int stg = s0 >> 4;

  f32x4 acc[4][2] = {};   // [h][st]
#pragma unroll
  for (int kc = 0; kc < 8; ++kc) {
    bf16x8 aW = as_bf(*(const u32x4*)(Wf + (((size_t)ot * 8 + kc) * 64 + lane) * 8));
    int h = kc >> 1, kch = kc & 1;
#pragma unroll
    for (int kk = 0; kk < KS; ++kk) {
      size_t kb = (size_t)(kk * 8 + b * NHEAD + h);
#pragma unroll
      for (int st = 0; st < 2; ++st) {
        bf16x8 bX = as_bf(*(const u32x4*)(Opb +
          (((kb * 256 + stg + st) * 2 + kch) * 64 + lane) * 8));
        acc[h][st] = MFMA16(aW, bX, acc[h][st]);
      }
    }
  }

  float inv[4][2];
#pragma unroll
  for (int h = 0; h < 4; ++h)
#pragma unroll
    for (int st = 0; st < 2; ++st) {
      size_t base = (size_t)(b * NHEAD + h) * SDIM + s0 + st * 16 + m;
      float lsum = 0.f;
#pragma unroll
      for (int kk = 0; kk < KS; ++kk) lsum += Lp[base + (size_t)kk * 8 * SDIM];
      inv[h][st] = 1.f / lsum;
    }

#pragma unroll
  for (int st = 0; st < 2; ++st)
#pragma unroll
    for (int r = 0; r < 4; ++r) {
      int o = o0 + w * 16 + quad * 4 + r;
      int s = s0 + st * 16 + m;
      float v = acc[0][st][r] * inv[0][st] + acc[1][st][r] * inv[1][st] +
                acc[2][st][r] * inv[2][st] + acc[3][st][r] * inv[3][st];
      size_t idx = ((size_t)b * CDIM + o) * SDIM + s;
      out[idx] = v + bias[o] + resid[idx];
    }
}

// ---------------------------------------------------------------------------
extern "C" void kernel_launch(void* const* d_in, const int* in_sizes, int n_in,
                              void* d_out, int out_size, void* d_ws, size_t ws_size,
                              hipStream_t stream) {
  const float* input = (const float*)d_in[0];
  const float* gnw   = (const float*)d_in[1];
  const float* gnb   = (const float*)d_in[2];
  const float* wq    = (const float*)d_in[3];
  const float* wo    = (const float*)d_in[4];
  const float* ob    = (const float*)d_in[5];
  float* out = (float*)d_out;

  char* ws = (char*)d_ws;
  unsigned short* Xf  = (unsigned short*)(ws);                        // 4 MB frag-linear GN(x)
  unsigned short* Qf  = (unsigned short*)(ws + (4ull  << 20));        // 4 MB
  unsigned short* Kf  = (unsigned short*)(ws + (8ull  << 20));        // 4 MB
  unsigned short* Vf  = (unsigned short*)(ws + (12ull << 20));        // 4 MB
  unsigned short* wqf = (unsigned short*)(ws + (20ull << 20));        // 384 KB frag-linear
  unsigned short* wof = (unsigned short*)(ws + (20ull << 20) + (1u << 19)); // 128 KB
  float2* Sp          = (float2*)(ws + (20ull << 20) + (3u << 18));   // 2 KB
  float* Lp           = (float*)(ws + (21ull << 20));                 // <=1 MB
  unsigned short* Opb = (unsigned short*)(ws + (22ull << 20));        // KS*4 MB

  k_prep<<<320, 256, 0, stream>>>(input, wq, wo, wqf, wof, Sp);
  k_gn_apply<<<dim3(64, NBATCH), 256, 0, stream>>>(input, Sp, gnw, gnb, Xf);
  k_qkv<<<dim3(12, 64, NBATCH), 256, 0, stream>>>(wqf, Xf, Qf, Kf, Vf);
  if (ws_size >= (54ull << 20)) {
    k_attn<8><<<dim3(32, NHEAD * NBATCH, 8), 256, 0, stream>>>(Qf, Kf, Vf, Opb, Lp);
    k_proj<8><<<dim3(4, 128, NBATCH), 256, 0, stream>>>(wof, Opb, Lp, ob, input, out);
  } else {
    k_attn<4><<<dim3(32, NHEAD * NBATCH, 4), 256, 0, stream>>>(Qf, Kf, Vf, Opb, Lp);
    k_proj<4><<<dim3(4, 128, NBATCH), 256, 0, stream>>>(wof, Opb, Lp, ob, input, out);
  }
}

// Round 10
// 146.584 us; speedup vs baseline: 1.5241x; 1.1977x over previous
//
#include <hip/hip_runtime.h>

// ---- types ----
typedef __bf16        bf16x8 __attribute__((ext_vector_type(8)));
typedef float         f32x4  __attribute__((ext_vector_type(4)));
typedef unsigned short u16x4 __attribute__((ext_vector_type(4)));
typedef unsigned short u16x8 __attribute__((ext_vector_type(8)));
typedef unsigned int  u32x4  __attribute__((ext_vector_type(4)));

#define MFMA16(a,b,c) __builtin_amdgcn_mfma_f32_16x16x32_bf16((a),(b),(c),0,0,0)

static __device__ __forceinline__ unsigned short f2bf(float f) {
  unsigned int u = __builtin_bit_cast(unsigned int, f);
  u += 0x7fffu + ((u >> 16) & 1u);          // RNE; inputs are finite
  return (unsigned short)(u >> 16);
}
static __device__ __forceinline__ unsigned int pk2rne(float a, float b) {
  return (unsigned int)f2bf(a) | ((unsigned int)f2bf(b) << 16);
}
// packed f32x2 -> bf16x2: 1 inst on gfx950, guarded fallback otherwise
static __device__ __forceinline__ unsigned int pkrn(float a, float b) {
#if __has_builtin(__builtin_amdgcn_cvt_pk_bf16_f32)
  auto r = __builtin_amdgcn_cvt_pk_bf16_f32(a, b);   // src0 -> low half
  return __builtin_bit_cast(unsigned int, r);
#else
  return pk2rne(a, b);
#endif
}
static __device__ __forceinline__ bf16x8 as_bf(u32x4 v) {
  return __builtin_bit_cast(bf16x8, v);
}
static __device__ __forceinline__ float bf2f(unsigned short u) {
  return __builtin_bit_cast(float, ((unsigned int)u) << 16);
}

// Problem constants
#define SDIM 4096
#define CDIM 256
#define NHEAD 4
#define HDIM 64
#define NBATCH 2
#define KSPLIT 4

// ---------------------------------------------------------------------------
// 1) merged prep: blocks 0..255 = GN partial stats; 256..319 = weight cast to
//    FRAG-LINEAR bf16:  Wf[(ot*8+kc)*64 + lane]*8 = W[ot*16+(l&15)][kc*32+(l>>4)*8 ..+8)
__global__ __launch_bounds__(256) void k_prep(const float* __restrict__ x,
                                              const float* __restrict__ wq,
                                              const float* __restrict__ wo,
                                              unsigned short* __restrict__ wqf,
                                              unsigned short* __restrict__ wof,
                                              float2* __restrict__ Sp) {
  int j = blockIdx.x, i = threadIdx.x;
  if (j < 256) {
    const float* p = x + (size_t)(j >> 3) * 65536 + (size_t)(j & 7) * 8192;
    float s = 0.f, sq = 0.f;
#pragma unroll
    for (int r = 0; r < 8; ++r) {
      float4 v = *(const float4*)(p + (r * 256 + i) * 4);
      s  += v.x + v.y + v.z + v.w;
      sq += v.x * v.x + v.y * v.y + v.z * v.z + v.w * v.w;
    }
    __shared__ float rs[256], rq[256];
    rs[i] = s; rq[i] = sq;
    __syncthreads();
    for (int off = 128; off > 0; off >>= 1) {
      if (i < off) { rs[i] += rs[i + off]; rq[i] += rq[i + off]; }
      __syncthreads();
    }
    if (i == 0) Sp[j] = make_float2(rs[0], rq[0]);
  } else {
    int t = (j - 256) * 256 + i;          // 2 frag-rows each
#pragma unroll
    for (int u = 0; u < 2; ++u) {
      int G = t * 2 + u;                  // 0..32767 = 24576 (wq) + 8192 (wo)
      const float* src; unsigned short* dst;
      if (G < 24576) {
        int tile = G >> 6, l = G & 63;
        src = wq + (size_t)((tile >> 3) * 16 + (l & 15)) * 256 + (tile & 7) * 32 + (l >> 4) * 8;
        dst = wqf + (size_t)G * 8;
      } else {
        int G2 = G - 24576, tile = G2 >> 6, l = G2 & 63;
        src = wo + (size_t)((tile >> 3) * 16 + (l & 15)) * 256 + (tile & 7) * 32 + (l >> 4) * 8;
        dst = wof + (size_t)G2 * 8;
      }
      float4 v0 = *(const float4*)src, v1 = *(const float4*)(src + 4);
      u16x8 r;
      r[0] = f2bf(v0.x); r[1] = f2bf(v0.y); r[2] = f2bf(v0.z); r[3] = f2bf(v0.w);
      r[4] = f2bf(v1.x); r[5] = f2bf(v1.y); r[6] = f2bf(v1.z); r[7] = f2bf(v1.w);
      *(u16x8*)dst = r;
    }
  }
}

// ---------------------------------------------------------------------------
// 2) GN apply + transpose: x[b][c][s] fp32 -> Xf frag-linear bf16
__global__ __launch_bounds__(256) void k_gn_apply(const float* __restrict__ x,
                                                  const float2* __restrict__ Sp,
                                                  const float* __restrict__ gnw,
                                                  const float* __restrict__ gnb,
                                                  unsigned short* __restrict__ Xf) {
  __shared__ __attribute__((aligned(16))) unsigned short sT[64 * 268];
  __shared__ float2 sStat[16];
  int b = blockIdx.y, s0 = blockIdx.x * 64;
  int i = threadIdx.x, lane = i & 63, w = i >> 6;
  if (i < 16) {
    float s = 0.f, sq = 0.f;
#pragma unroll
    for (int u = 0; u < 8; ++u) {
      float2 v = Sp[(b * 16 + i) * 8 + u];
      s += v.x; sq += v.y;
    }
    float mean = s * (1.f / 65536.f);
    float var  = sq * (1.f / 65536.f) - mean * mean;
    sStat[i] = make_float2(mean, rsqrtf(var + 1e-5f));
  }
  __syncthreads();
#pragma unroll 4
  for (int r = 0; r < 64; ++r) {
    int c = r * 4 + w;
    float v = x[((size_t)(b * CDIM + c)) * SDIM + s0 + lane];
    float2 st = sStat[c >> 4];
    float nv = (v - st.x) * st.y * gnw[c] + gnb[c];
    sT[lane * 268 + c] = f2bf(nv);
  }
  __syncthreads();
  int l = i & 63, fr = i >> 6;
#pragma unroll
  for (int g = 0; g < 8; ++g) {
    int tile = fr * 8 + g, st = tile >> 3, kc = tile & 7;
    const unsigned short* src = &sT[(st * 16 + (l & 15)) * 268 + kc * 32 + (l >> 4) * 8];
    u16x4 lo = *(const u16x4*)src, hi = *(const u16x4*)(src + 4);
    unsigned short* dst = Xf + (((size_t)(b * 256 + (s0 >> 4) + st) * 8 + kc) * 64 + l) * 8;
    *(u16x4*)dst = lo;
    *(u16x4*)(dst + 4) = hi;
  }
}

// ---------------------------------------------------------------------------
// 3) QKV GEMM (barrier-free K-loop, frag-linear operands), epilogue repacks:
//    Qf/Kf[bh][t16=s/16][ks=d/32][lane][8]  (Q pre-scaled by log2(e)/16)
//    Vf[bh][t32=s/32][dt=d/16][lane][8]
__global__ __launch_bounds__(256) void k_qkv(const unsigned short* __restrict__ Wf,
                                             const unsigned short* __restrict__ Xf,
                                             unsigned short* __restrict__ Qf,
                                             unsigned short* __restrict__ Kf,
                                             unsigned short* __restrict__ Vf) {
  __shared__ __attribute__((aligned(16))) unsigned short sB[64 * 68];  // epilogue bounce
  int b = blockIdx.z, s0 = blockIdx.y * 64, o0 = blockIdx.x * 64;
  int i = threadIdx.x, lane = i & 63, w = i >> 6;
  int quad = lane >> 4, m = lane & 15;
  int ot = blockIdx.x * 4 + w;
  int stg = s0 >> 4;

  f32x4 acc[4] = {};
#pragma unroll
  for (int kc = 0; kc < 8; ++kc) {
    bf16x8 aW = as_bf(*(const u32x4*)(Wf + (((size_t)ot * 8 + kc) * 64 + lane) * 8));
#pragma unroll
    for (int st = 0; st < 4; ++st) {
      bf16x8 bX = as_bf(*(const u32x4*)(Xf + ((((size_t)b * 256 + stg + st) * 8 + kc) * 64 + lane) * 8));
      acc[st] = MFMA16(aW, bX, acc[st]);
    }
  }

  int sec = (o0 >> 6) % 3;             // 0=Q, 1=K, 2=V
  int h   = o0 / 192;
  int bh  = b * NHEAD + h;
  float qs = (sec == 0) ? 0.09016844f : 1.0f;   // log2(e)/16 folded into Q
#pragma unroll
  for (int st = 0; st < 4; ++st) {
    uint2 pk = make_uint2(pk2rne(acc[st][0] * qs, acc[st][1] * qs),
                          pk2rne(acc[st][2] * qs, acc[st][3] * qs));
    *(uint2*)&sB[(st * 16 + m) * 68 + w * 16 + quad * 4] = pk;
  }
  __syncthreads();
  int lp = i & 63, qp = lp >> 4, mp = lp & 15, t = i >> 6;
  if (sec < 2) {
    unsigned short* base = (sec == 0) ? Qf : Kf;
#pragma unroll
    for (int ks = 0; ks < 2; ++ks) {
      const unsigned short* src = &sB[(t * 16 + mp) * 68 + ks * 32 + qp * 8];
      u16x4 lo = *(const u16x4*)src;
      u16x4 hi = *(const u16x4*)(src + 4);
      unsigned short* dst = base + ((((size_t)bh * 256 + (s0 >> 4) + t) * 2 + ks) * 64 + lp) * 8;
      *(u16x4*)dst = lo;
      *(u16x4*)(dst + 4) = hi;
    }
  } else {
    int kt32l = t >> 1, dts = (t & 1) * 2;
#pragma unroll
    for (int dd = 0; dd < 2; ++dd) {
      int dt = dts + dd;
      u16x8 v;
#pragma unroll
      for (int jj = 0; jj < 8; ++jj)
        v[jj] = sB[(kt32l * 32 + qp * 8 + jj) * 68 + dt * 16 + mp];
      unsigned short* dst = Vf + ((((size_t)bh * 128 + (s0 >> 5) + kt32l) * 4 + dt) * 64 + lp) * 8;
      *(u16x8*)dst = v;
    }
  }
}

// ---------------------------------------------------------------------------
// 4) Flash attention (R7 body, KSPLIT=4): barrier-free main loop, K/V frags
//    direct from global. Epilogue writes Opb in PROJ-B-FRAG-LINEAR layout
//    Opb[kkbh][t16=q/16][kc=d/32][lane][8]; Lp fp32 [kkbh][q].
template <int KS>
__global__ __launch_bounds__(256, 4) void k_attn(const unsigned short* __restrict__ Qf,
                                                 const unsigned short* __restrict__ Kf,
                                                 const unsigned short* __restrict__ Vf,
                                                 unsigned short* __restrict__ Opb,
                                                 float* __restrict__ Lp) {
  // main loop: per-wave sP (4 x 32q x 40); epilogue: obuf bf16 [128 q][72]
  __shared__ __attribute__((aligned(16))) unsigned short smem[128 * 72];
  int bh = blockIdx.y, kk = blockIdx.z;
  int i = threadIdx.x, lane = i & 63, w = i >> 6;
  int quad = lane >> 4, m = lane & 15;
  constexpr int ITERS = SDIM / KS / 32;
  unsigned short* sP = smem + w * 1280;   // per-wave [32q][40]

  bf16x8 bq[2][2];
#pragma unroll
  for (int qt = 0; qt < 2; ++qt)
#pragma unroll
    for (int ks = 0; ks < 2; ++ks)
      bq[qt][ks] = as_bf(*(const u32x4*)(Qf +
        ((((size_t)bh * 256 + (blockIdx.x * 8 + w * 2 + qt)) * 2 + ks) * 64 + lane) * 8));

  f32x4 oacc[2][4] = {};
  float li[2] = {0.f, 0.f};

  for (int it = 0; it < ITERS; ++it) {
    bf16x8 av[4];
    int kb32 = kk * ITERS + it;
#pragma unroll
    for (int dt = 0; dt < 4; ++dt)
      av[dt] = as_bf(*(const u32x4*)(Vf +
        ((((size_t)bh * 128 + kb32) * 4 + dt) * 64 + lane) * 8));

    bf16x8 ak[2][2];
    int kb16 = kk * (ITERS * 2) + it * 2;
#pragma unroll
    for (int ky = 0; ky < 2; ++ky)
#pragma unroll
      for (int ks = 0; ks < 2; ++ks)
        ak[ky][ks] = as_bf(*(const u32x4*)(Kf +
          ((((size_t)bh * 256 + kb16 + ky) * 2 + ks) * 64 + lane) * 8));

#pragma unroll
    for (int qt = 0; qt < 2; ++qt) {
      f32x4 sc0 = {-18.f, -18.f, -18.f, -18.f};   // fixed-max shift in C-init
      f32x4 sc1 = sc0;
      sc0 = MFMA16(ak[0][0], bq[qt][0], sc0);
      sc0 = MFMA16(ak[0][1], bq[qt][1], sc0);
      sc1 = MFMA16(ak[1][0], bq[qt][0], sc1);
      sc1 = MFMA16(ak[1][1], bq[qt][1], sc1);
      float p[8];
#pragma unroll
      for (int r = 0; r < 4; ++r) {
        p[r]     = __builtin_amdgcn_exp2f(sc0[r]);
        p[4 + r] = __builtin_amdgcn_exp2f(sc1[r]);
      }
      li[qt] += ((p[0] + p[1]) + (p[2] + p[3])) + ((p[4] + p[5]) + (p[6] + p[7]));
      int row = (qt * 16 + m) * 40;
      *(uint2*)&sP[row + quad * 4]      = make_uint2(pkrn(p[0], p[1]), pkrn(p[2], p[3]));
      *(uint2*)&sP[row + 16 + quad * 4] = make_uint2(pkrn(p[4], p[5]), pkrn(p[6], p[7]));
    }
#pragma unroll
    for (int qt = 0; qt < 2; ++qt) {
      bf16x8 bp = *(const bf16x8*)&sP[(qt * 16 + m) * 40 + quad * 8];
#pragma unroll
      for (int dt = 0; dt < 4; ++dt)
        oacc[qt][dt] = MFMA16(av[dt], bp, oacc[qt][dt]);
    }
  }

  // li: quads hold disjoint key subsets -> reduce, store
  size_t lg = (size_t)(kk * 8 + bh) * SDIM + blockIdx.x * 128 + w * 32;
#pragma unroll
  for (int qt = 0; qt < 2; ++qt) {
    li[qt] += __shfl_xor(li[qt], 16);
    li[qt] += __shfl_xor(li[qt], 32);
  }
  if (quad == 0) {
#pragma unroll
    for (int qt = 0; qt < 2; ++qt) Lp[lg + qt * 16 + m] = li[qt];
  }

  // O: bounce through LDS into proj-B-frag-linear Opb
  __syncthreads();   // all waves done with sP
  unsigned short* ob = smem;   // [128 q][72]
#pragma unroll
  for (int qt = 0; qt < 2; ++qt)
#pragma unroll
    for (int dt = 0; dt < 4; ++dt) {
      int ql = w * 32 + qt * 16 + m, d0 = dt * 16 + quad * 4;
      *(unsigned int*)&ob[ql * 72 + d0]     = pkrn(oacc[qt][dt][0], oacc[qt][dt][1]);
      *(unsigned int*)&ob[ql * 72 + d0 + 2] = pkrn(oacc[qt][dt][2], oacc[qt][dt][3]);
    }
  __syncthreads();
  int l = i & 63, sub = i >> 6, mp = l & 15, qp = l >> 4;
#pragma unroll
  for (int tt = 0; tt < 2; ++tt)
#pragma unroll
    for (int kc = 0; kc < 2; ++kc) {
      int t16l = sub * 2 + tt;
      u16x8 v = *(const u16x8*)&ob[(t16l * 16 + mp) * 72 + kc * 32 + qp * 8];
      size_t idx = ((((size_t)(kk * 8 + bh) * 256 + blockIdx.x * 8 + t16l) * 2 + kc) * 64 + l) * 8;
      *(u16x8*)(Opb + idx) = v;
    }
}

// ---------------------------------------------------------------------------
// 5) FUSED combine + proj: block = (16 s) x (all 256 o).
//    Phase 1: sum KSPLIT partials in fp32, normalize by per-head 1/l,
//             pack bf16 into LDS P-tile [8 kc][64 lane][8] (B-frag-linear).
//             (Normalizing before the linear proj is exact.)
//    Phase 2: K=256 GEMM from LDS; W frag-linear from global (L2-resident).
//    Opb read EXACTLY ONCE (R9's version redid the GEMM per split = 8x K).
__global__ __launch_bounds__(256, 4) void k_proj(const unsigned short* __restrict__ Wf,
                                                 const unsigned short* __restrict__ Opb,
                                                 const float* __restrict__ Lp,
                                                 const float* __restrict__ bias,
                                                 const float* __restrict__ resid,
                                                 float* __restrict__ out) {
  __shared__ __attribute__((aligned(16))) unsigned short sPc[8 * 512];
  __shared__ float sL[4][16];
  int b = blockIdx.y, t16g = blockIdx.x, s0 = t16g * 16;
  int i = threadIdx.x, lane = i & 63, w = i >> 6;
  int quad = lane >> 4, m = lane & 15;

  if (i < 64) {
    int h = i >> 4, s = i & 15;
    float lsum = 0.f;
#pragma unroll
    for (int kk = 0; kk < KSPLIT; ++kk)
      lsum += Lp[(size_t)(kk * 8 + b * NHEAD + h) * SDIM + s0 + s];
    sL[h][s] = 1.f / lsum;
  }
  __syncthreads();

  // phase 1: combine -> LDS (each thread: 2 frag-rows of 8 elems)
  int fr = i >> 6, l = i & 63;
#pragma unroll
  for (int f = 0; f < 2; ++f) {
    int kcq = fr * 2 + f, h = kcq >> 1, kch = kcq & 1;
    float o[8] = {};
#pragma unroll
    for (int kk = 0; kk < KSPLIT; ++kk) {
      const unsigned short* p = Opb +
        ((((size_t)(kk * 8 + b * NHEAD + h) * 256 + t16g) * 2 + kch) * 64 + l) * 8;
      u16x8 v = *(const u16x8*)p;
#pragma unroll
      for (int e = 0; e < 8; ++e) o[e] += bf2f(v[e]);
    }
    float inv = sL[h][l & 15];
    unsigned int dw[4];
#pragma unroll
    for (int e = 0; e < 4; ++e) dw[e] = pkrn(o[2 * e] * inv, o[2 * e + 1] * inv);
    *(u32x4*)&sPc[kcq * 512 + l * 8] = u32x4{dw[0], dw[1], dw[2], dw[3]};
  }
  __syncthreads();

  // phase 2: K=256 GEMM; wave w covers o-tiles w*4..w*4+3
  f32x4 acc[4] = {};
#pragma unroll
  for (int kc = 0; kc < 8; ++kc) {
    bf16x8 bP = *(const bf16x8*)&sPc[kc * 512 + lane * 8];
#pragma unroll
    for (int j = 0; j < 4; ++j) {
      int ot = w * 4 + j;
      bf16x8 aW = as_bf(*(const u32x4*)(Wf + (((size_t)ot * 8 + kc) * 64 + lane) * 8));
      acc[j] = MFMA16(aW, bP, acc[j]);
    }
  }

#pragma unroll
  for (int j = 0; j < 4; ++j)
#pragma unroll
    for (int r = 0; r < 4; ++r) {
      int o = (w * 4 + j) * 16 + quad * 4 + r;
      int s = s0 + m;
      size_t idx = ((size_t)b * CDIM + o) * SDIM + s;
      out[idx] = acc[j][r] + bias[o] + resid[idx];
    }
}

// ---------------------------------------------------------------------------
extern "C" void kernel_launch(void* const* d_in, const int* in_sizes, int n_in,
                              void* d_out, int out_size, void* d_ws, size_t ws_size,
                              hipStream_t stream) {
  const float* input = (const float*)d_in[0];
  const float* gnw   = (const float*)d_in[1];
  const float* gnb   = (const float*)d_in[2];
  const float* wq    = (const float*)d_in[3];
  const float* wo    = (const float*)d_in[4];
  const float* ob    = (const float*)d_in[5];
  float* out = (float*)d_out;

  char* ws = (char*)d_ws;
  unsigned short* Xf  = (unsigned short*)(ws);                        // 4 MB frag-linear GN(x)
  unsigned short* Qf  = (unsigned short*)(ws + (4ull  << 20));        // 4 MB
  unsigned short* Kf  = (unsigned short*)(ws + (8ull  << 20));        // 4 MB
  unsigned short* Vf  = (unsigned short*)(ws + (12ull << 20));        // 4 MB
  unsigned short* wqf = (unsigned short*)(ws + (20ull << 20));        // 384 KB frag-linear
  unsigned short* wof = (unsigned short*)(ws + (20ull << 20) + (1u << 19)); // 128 KB
  float2* Sp          = (float2*)(ws + (20ull << 20) + (3u << 18));   // 2 KB
  float* Lp           = (float*)(ws + (21ull << 20));                 // 512 KB
  unsigned short* Opb = (unsigned short*)(ws + (22ull << 20));        // 16 MB

  k_prep<<<320, 256, 0, stream>>>(input, wq, wo, wqf, wof, Sp);
  k_gn_apply<<<dim3(64, NBATCH), 256, 0, stream>>>(input, Sp, gnw, gnb, Xf);
  k_qkv<<<dim3(12, 64, NBATCH), 256, 0, stream>>>(wqf, Xf, Qf, Kf, Vf);
  k_attn<KSPLIT><<<dim3(32, NHEAD * NBATCH, KSPLIT), 256, 0, stream>>>(Qf, Kf, Vf, Opb, Lp);
  k_proj<<<dim3(256, NBATCH), 256, 0, stream>>>(wof, Opb, Lp, ob, input, out);
}

// Round 11
// 146.578 us; speedup vs baseline: 1.5241x; 1.0000x over previous
//
#include <hip/hip_runtime.h>

// ---- types ----
typedef __bf16        bf16x8 __attribute__((ext_vector_type(8)));
typedef float         f32x4  __attribute__((ext_vector_type(4)));
typedef unsigned short u16x4 __attribute__((ext_vector_type(4)));
typedef unsigned short u16x8 __attribute__((ext_vector_type(8)));
typedef unsigned int  u32x4  __attribute__((ext_vector_type(4)));

#define MFMA16(a,b,c) __builtin_amdgcn_mfma_f32_16x16x32_bf16((a),(b),(c),0,0,0)

static __device__ __forceinline__ unsigned short f2bf(float f) {
  unsigned int u = __builtin_bit_cast(unsigned int, f);
  u += 0x7fffu + ((u >> 16) & 1u);          // RNE; inputs are finite
  return (unsigned short)(u >> 16);
}
static __device__ __forceinline__ unsigned int pk2rne(float a, float b) {
  return (unsigned int)f2bf(a) | ((unsigned int)f2bf(b) << 16);
}
// packed f32x2 -> bf16x2: 1 inst on gfx950, guarded fallback otherwise
static __device__ __forceinline__ unsigned int pkrn(float a, float b) {
#if __has_builtin(__builtin_amdgcn_cvt_pk_bf16_f32)
  auto r = __builtin_amdgcn_cvt_pk_bf16_f32(a, b);   // src0 -> low half
  return __builtin_bit_cast(unsigned int, r);
#else
  return pk2rne(a, b);
#endif
}
static __device__ __forceinline__ bf16x8 as_bf(u32x4 v) {
  return __builtin_bit_cast(bf16x8, v);
}
static __device__ __forceinline__ float bf2f(unsigned short u) {
  return __builtin_bit_cast(float, ((unsigned int)u) << 16);
}

// Problem constants
#define SDIM 4096
#define CDIM 256
#define NHEAD 4
#define HDIM 64
#define NBATCH 2
#define KSPLIT 4

// ---------------------------------------------------------------------------
// 1) merged prep: blocks 0..255 = GN partial stats; 256..319 = weight cast to
//    FRAG-LINEAR bf16:  Wf[(ot*8+kc)*64 + lane]*8 = W[ot*16+(l&15)][kc*32+(l>>4)*8 ..+8)
__global__ __launch_bounds__(256) void k_prep(const float* __restrict__ x,
                                              const float* __restrict__ wq,
                                              const float* __restrict__ wo,
                                              unsigned short* __restrict__ wqf,
                                              unsigned short* __restrict__ wof,
                                              float2* __restrict__ Sp) {
  int j = blockIdx.x, i = threadIdx.x;
  if (j < 256) {
    const float* p = x + (size_t)(j >> 3) * 65536 + (size_t)(j & 7) * 8192;
    float s = 0.f, sq = 0.f;
#pragma unroll
    for (int r = 0; r < 8; ++r) {
      float4 v = *(const float4*)(p + (r * 256 + i) * 4);
      s  += v.x + v.y + v.z + v.w;
      sq += v.x * v.x + v.y * v.y + v.z * v.z + v.w * v.w;
    }
    __shared__ float rs[256], rq[256];
    rs[i] = s; rq[i] = sq;
    __syncthreads();
    for (int off = 128; off > 0; off >>= 1) {
      if (i < off) { rs[i] += rs[i + off]; rq[i] += rq[i + off]; }
      __syncthreads();
    }
    if (i == 0) Sp[j] = make_float2(rs[0], rq[0]);
  } else {
    int t = (j - 256) * 256 + i;          // 2 frag-rows each
#pragma unroll
    for (int u = 0; u < 2; ++u) {
      int G = t * 2 + u;                  // 0..32767 = 24576 (wq) + 8192 (wo)
      const float* src; unsigned short* dst;
      if (G < 24576) {
        int tile = G >> 6, l = G & 63;
        src = wq + (size_t)((tile >> 3) * 16 + (l & 15)) * 256 + (tile & 7) * 32 + (l >> 4) * 8;
        dst = wqf + (size_t)G * 8;
      } else {
        int G2 = G - 24576, tile = G2 >> 6, l = G2 & 63;
        src = wo + (size_t)((tile >> 3) * 16 + (l & 15)) * 256 + (tile & 7) * 32 + (l >> 4) * 8;
        dst = wof + (size_t)G2 * 8;
      }
      float4 v0 = *(const float4*)src, v1 = *(const float4*)(src + 4);
      u16x8 r;
      r[0] = f2bf(v0.x); r[1] = f2bf(v0.y); r[2] = f2bf(v0.z); r[3] = f2bf(v0.w);
      r[4] = f2bf(v1.x); r[5] = f2bf(v1.y); r[6] = f2bf(v1.z); r[7] = f2bf(v1.w);
      *(u16x8*)dst = r;
    }
  }
}

// ---------------------------------------------------------------------------
// 2) GN apply + transpose: x[b][c][s] fp32 -> Xf frag-linear bf16.
//    Re-tiled 64s x 64c per block -> 512 blocks (was 128 = 0.5/CU).
__global__ __launch_bounds__(256) void k_gn_apply(const float* __restrict__ x,
                                                  const float2* __restrict__ Sp,
                                                  const float* __restrict__ gnw,
                                                  const float* __restrict__ gnb,
                                                  unsigned short* __restrict__ Xf) {
  __shared__ __attribute__((aligned(16))) unsigned short sT[64 * 68];
  __shared__ float2 sStat[16];
  int b = blockIdx.z, s0 = blockIdx.x * 64, c0 = blockIdx.y * 64;
  int i = threadIdx.x, lane = i & 63, w = i >> 6;
  if (i < 16) {
    float s = 0.f, sq = 0.f;
#pragma unroll
    for (int u = 0; u < 8; ++u) {
      float2 v = Sp[(b * 16 + i) * 8 + u];
      s += v.x; sq += v.y;
    }
    float mean = s * (1.f / 65536.f);
    float var  = sq * (1.f / 65536.f) - mean * mean;
    sStat[i] = make_float2(mean, rsqrtf(var + 1e-5f));
  }
  __syncthreads();
#pragma unroll 4
  for (int r = 0; r < 16; ++r) {
    int c = c0 + r * 4 + w;
    float v = x[((size_t)(b * CDIM + c)) * SDIM + s0 + lane];
    float2 st = sStat[c >> 4];
    float nv = (v - st.x) * st.y * gnw[c] + gnb[c];
    sT[lane * 68 + (c - c0)] = f2bf(nv);
  }
  __syncthreads();
  int l = i & 63, t = i >> 6, mp = l & 15, qp = l >> 4;
#pragma unroll
  for (int kcl = 0; kcl < 2; ++kcl) {
    const unsigned short* src = &sT[(t * 16 + mp) * 68 + kcl * 32 + qp * 8];
    u16x4 lo = *(const u16x4*)src, hi = *(const u16x4*)(src + 4);
    unsigned short* dst = Xf +
      (((size_t)(b * 256 + (s0 >> 4) + t) * 8 + (c0 >> 5) + kcl) * 64 + l) * 8;
    *(u16x4*)dst = lo;
    *(u16x4*)(dst + 4) = hi;
  }
}

// ---------------------------------------------------------------------------
// 3) QKV GEMM (barrier-free K-loop, frag-linear operands), epilogue repacks:
//    Qf/Kf[bh][t16=s/16][ks=d/32][lane][8]  (Q pre-scaled by log2(e)/16)
//    Vf[bh][t32=s/32][dt=d/16][lane][8] NEW content:
//      elems 0-3 = V[kt+4*quad+j][dt*16+m], elems 4-7 = V[kt+16+4*quad+j][..]
//      (matches the x32 A-operand slots used by the register-direct PV)
__global__ __launch_bounds__(256) void k_qkv(const unsigned short* __restrict__ Wf,
                                             const unsigned short* __restrict__ Xf,
                                             unsigned short* __restrict__ Qf,
                                             unsigned short* __restrict__ Kf,
                                             unsigned short* __restrict__ Vf) {
  __shared__ __attribute__((aligned(16))) unsigned short sB[64 * 68];  // epilogue bounce
  int b = blockIdx.z, s0 = blockIdx.y * 64, o0 = blockIdx.x * 64;
  int i = threadIdx.x, lane = i & 63, w = i >> 6;
  int quad = lane >> 4, m = lane & 15;
  int ot = blockIdx.x * 4 + w;
  int stg = s0 >> 4;

  f32x4 acc[4] = {};
#pragma unroll
  for (int kc = 0; kc < 8; ++kc) {
    bf16x8 aW = as_bf(*(const u32x4*)(Wf + (((size_t)ot * 8 + kc) * 64 + lane) * 8));
#pragma unroll
    for (int st = 0; st < 4; ++st) {
      bf16x8 bX = as_bf(*(const u32x4*)(Xf + ((((size_t)b * 256 + stg + st) * 8 + kc) * 64 + lane) * 8));
      acc[st] = MFMA16(aW, bX, acc[st]);
    }
  }

  int sec = (o0 >> 6) % 3;             // 0=Q, 1=K, 2=V
  int h   = o0 / 192;
  int bh  = b * NHEAD + h;
  float qs = (sec == 0) ? 0.09016844f : 1.0f;   // log2(e)/16 folded into Q
#pragma unroll
  for (int st = 0; st < 4; ++st) {
    uint2 pk = make_uint2(pk2rne(acc[st][0] * qs, acc[st][1] * qs),
                          pk2rne(acc[st][2] * qs, acc[st][3] * qs));
    *(uint2*)&sB[(st * 16 + m) * 68 + w * 16 + quad * 4] = pk;
  }
  __syncthreads();
  int lp = i & 63, qp = lp >> 4, mp = lp & 15, t = i >> 6;
  if (sec < 2) {
    unsigned short* base = (sec == 0) ? Qf : Kf;
#pragma unroll
    for (int ks = 0; ks < 2; ++ks) {
      const unsigned short* src = &sB[(t * 16 + mp) * 68 + ks * 32 + qp * 8];
      u16x4 lo = *(const u16x4*)src;
      u16x4 hi = *(const u16x4*)(src + 4);
      unsigned short* dst = base + ((((size_t)bh * 256 + (s0 >> 4) + t) * 2 + ks) * 64 + lp) * 8;
      *(u16x4*)dst = lo;
      *(u16x4*)(dst + 4) = hi;
    }
  } else {
    int kt32l = t >> 1, dts = (t & 1) * 2;
#pragma unroll
    for (int dd = 0; dd < 2; ++dd) {
      int dt = dts + dd;
      u16x8 v;
#pragma unroll
      for (int jj = 0; jj < 4; ++jj) {
        v[jj]     = sB[(kt32l * 32 + qp * 4 + jj) * 68 + dt * 16 + mp];
        v[4 + jj] = sB[(kt32l * 32 + 16 + qp * 4 + jj) * 68 + dt * 16 + mp];
      }
      unsigned short* dst = Vf + ((((size_t)bh * 128 + (s0 >> 5) + kt32l) * 4 + dt) * 64 + lp) * 8;
      *(u16x8*)dst = v;
    }
  }
}

// ---------------------------------------------------------------------------
// 4) Flash attention v7: ZERO LDS in the main loop. P stays in registers:
//    QK's C-layout gives lane (quad,m) P^T[key=kt+4q+r][q=m]; with Vf's new
//    packing, B0=[p0..3,0,0,0,0] / B1=[0,0,0,0,p4..7] against the full V frag
//    contract exactly those keys (zero slots kill the other half). Verified
//    x32 mappings only. Epilogue (unchanged): Opb proj-B-frag-linear + Lp.
template <int KS>
__global__ __launch_bounds__(256, 4) void k_attn(const unsigned short* __restrict__ Qf,
                                                 const unsigned short* __restrict__ Kf,
                                                 const unsigned short* __restrict__ Vf,
                                                 unsigned short* __restrict__ Opb,
                                                 float* __restrict__ Lp) {
  __shared__ __attribute__((aligned(16))) unsigned short smem[128 * 72];  // epilogue only
  int bh = blockIdx.y, kk = blockIdx.z;
  int i = threadIdx.x, lane = i & 63, w = i >> 6;
  int quad = lane >> 4, m = lane & 15;
  constexpr int ITERS = SDIM / KS / 32;

  bf16x8 bq[2][2];
#pragma unroll
  for (int qt = 0; qt < 2; ++qt)
#pragma unroll
    for (int ks = 0; ks < 2; ++ks)
      bq[qt][ks] = as_bf(*(const u32x4*)(Qf +
        ((((size_t)bh * 256 + (blockIdx.x * 8 + w * 2 + qt)) * 2 + ks) * 64 + lane) * 8));

  f32x4 oacc[2][4] = {};
  float li[2] = {0.f, 0.f};

  for (int it = 0; it < ITERS; ++it) {
    u32x4 vf[4];
    int kb32 = kk * ITERS + it;
#pragma unroll
    for (int dt = 0; dt < 4; ++dt)
      vf[dt] = *(const u32x4*)(Vf +
        ((((size_t)bh * 128 + kb32) * 4 + dt) * 64 + lane) * 8);

    bf16x8 ak[2][2];
    int kb16 = kk * (ITERS * 2) + it * 2;
#pragma unroll
    for (int ky = 0; ky < 2; ++ky)
#pragma unroll
      for (int ks = 0; ks < 2; ++ks)
        ak[ky][ks] = as_bf(*(const u32x4*)(Kf +
          ((((size_t)bh * 256 + kb16 + ky) * 2 + ks) * 64 + lane) * 8));

#pragma unroll
    for (int qt = 0; qt < 2; ++qt) {
      f32x4 sc0 = {-18.f, -18.f, -18.f, -18.f};   // fixed-max shift in C-init
      f32x4 sc1 = sc0;
      sc0 = MFMA16(ak[0][0], bq[qt][0], sc0);
      sc0 = MFMA16(ak[0][1], bq[qt][1], sc0);
      sc1 = MFMA16(ak[1][0], bq[qt][0], sc1);
      sc1 = MFMA16(ak[1][1], bq[qt][1], sc1);
      float p[8];
#pragma unroll
      for (int r = 0; r < 4; ++r) {
        p[r]     = __builtin_amdgcn_exp2f(sc0[r]);
        p[4 + r] = __builtin_amdgcn_exp2f(sc1[r]);
      }
      li[qt] += ((p[0] + p[1]) + (p[2] + p[3])) + ((p[4] + p[5]) + (p[6] + p[7]));
      // register-direct P: keys 4quad+j (B0) and 16+4quad+j (B1)
      bf16x8 b0 = as_bf(u32x4{pkrn(p[0], p[1]), pkrn(p[2], p[3]), 0u, 0u});
      bf16x8 b1 = as_bf(u32x4{0u, 0u, pkrn(p[4], p[5]), pkrn(p[6], p[7])});
#pragma unroll
      for (int dt = 0; dt < 4; ++dt) {
        oacc[qt][dt] = MFMA16(as_bf(vf[dt]), b0, oacc[qt][dt]);
        oacc[qt][dt] = MFMA16(as_bf(vf[dt]), b1, oacc[qt][dt]);
      }
    }
  }

  // li: quads hold disjoint key subsets -> reduce, store
  size_t lg = (size_t)(kk * 8 + bh) * SDIM + blockIdx.x * 128 + w * 32;
#pragma unroll
  for (int qt = 0; qt < 2; ++qt) {
    li[qt] += __shfl_xor(li[qt], 16);
    li[qt] += __shfl_xor(li[qt], 32);
  }
  if (quad == 0) {
#pragma unroll
    for (int qt = 0; qt < 2; ++qt) Lp[lg + qt * 16 + m] = li[qt];
  }

  // O: bounce through LDS into proj-B-frag-linear Opb
  __syncthreads();
  unsigned short* ob = smem;   // [128 q][72]
#pragma unroll
  for (int qt = 0; qt < 2; ++qt)
#pragma unroll
    for (int dt = 0; dt < 4; ++dt) {
      int ql = w * 32 + qt * 16 + m, d0 = dt * 16 + quad * 4;
      *(unsigned int*)&ob[ql * 72 + d0]     = pkrn(oacc[qt][dt][0], oacc[qt][dt][1]);
      *(unsigned int*)&ob[ql * 72 + d0 + 2] = pkrn(oacc[qt][dt][2], oacc[qt][dt][3]);
    }
  __syncthreads();
  int l = i & 63, sub = i >> 6, mp = l & 15, qp = l >> 4;
#pragma unroll
  for (int tt = 0; tt < 2; ++tt)
#pragma unroll
    for (int kc = 0; kc < 2; ++kc) {
      int t16l = sub * 2 + tt;
      u16x8 v = *(const u16x8*)&ob[(t16l * 16 + mp) * 72 + kc * 32 + qp * 8];
      size_t idx = ((((size_t)(kk * 8 + bh) * 256 + blockIdx.x * 8 + t16l) * 2 + kc) * 64 + l) * 8;
      *(u16x8*)(Opb + idx) = v;
    }
}

// ---------------------------------------------------------------------------
// 5) FUSED combine + proj: block = (16 s) x (all 256 o).
//    Phase 1: sum KSPLIT partials fp32, normalize per-head, pack to LDS.
//    Phase 2: single K=256 GEMM from LDS (W frag-linear, L2-resident).
__global__ __launch_bounds__(256, 4) void k_proj(const unsigned short* __restrict__ Wf,
                                                 const unsigned short* __restrict__ Opb,
                                                 const float* __restrict__ Lp,
                                                 const float* __restrict__ bias,
                                                 const float* __restrict__ resid,
                                                 float* __restrict__ out) {
  __shared__ __attribute__((aligned(16))) unsigned short sPc[8 * 512];
  __shared__ float sL[4][16];
  int b = blockIdx.y, t16g = blockIdx.x, s0 = t16g * 16;
  int i = threadIdx.x, lane = i & 63, w = i >> 6;
  int quad = lane >> 4, m = lane & 15;

  if (i < 64) {
    int h = i >> 4, s = i & 15;
    float lsum = 0.f;
#pragma unroll
    for (int kk = 0; kk < KSPLIT; ++kk)
      lsum += Lp[(size_t)(kk * 8 + b * NHEAD + h) * SDIM + s0 + s];
    sL[h][s] = 1.f / lsum;
  }
  __syncthreads();

  int fr = i >> 6, l = i & 63;
#pragma unroll
  for (int f = 0; f < 2; ++f) {
    int kcq = fr * 2 + f, h = kcq >> 1, kch = kcq & 1;
    float o[8] = {};
#pragma unroll
    for (int kk = 0; kk < KSPLIT; ++kk) {
      const unsigned short* p = Opb +
        ((((size_t)(kk * 8 + b * NHEAD + h) * 256 + t16g) * 2 + kch) * 64 + l) * 8;
      u16x8 v = *(const u16x8*)p;
#pragma unroll
      for (int e = 0; e < 8; ++e) o[e] += bf2f(v[e]);
    }
    float inv = sL[h][l & 15];
    unsigned int dw[4];
#pragma unroll
    for (int e = 0; e < 4; ++e) dw[e] = pkrn(o[2 * e] * inv, o[2 * e + 1] * inv);
    *(u32x4*)&sPc[kcq * 512 + l * 8] = u32x4{dw[0], dw[1], dw[2], dw[3]};
  }
  __syncthreads();

  f32x4 acc[4] = {};
#pragma unroll
  for (int kc = 0; kc < 8; ++kc) {
    bf16x8 bP = *(const bf16x8*)&sPc[kc * 512 + lane * 8];
#pragma unroll
    for (int j = 0; j < 4; ++j) {
      int ot = w * 4 + j;
      bf16x8 aW = as_bf(*(const u32x4*)(Wf + (((size_t)ot * 8 + kc) * 64 + lane) * 8));
      acc[j] = MFMA16(aW, bP, acc[j]);
    }
  }

#pragma unroll
  for (int j = 0; j < 4; ++j)
#pragma unroll
    for (int r = 0; r < 4; ++r) {
      int o = (w * 4 + j) * 16 + quad * 4 + r;
      int s = s0 + m;
      size_t idx = ((size_t)b * CDIM + o) * SDIM + s;
      out[idx] = acc[j][r] + bias[o] + resid[idx];
    }
}

// ---------------------------------------------------------------------------
extern "C" void kernel_launch(void* const* d_in, const int* in_sizes, int n_in,
                              void* d_out, int out_size, void* d_ws, size_t ws_size,
                              hipStream_t stream) {
  const float* input = (const float*)d_in[0];
  const float* gnw   = (const float*)d_in[1];
  const float* gnb   = (const float*)d_in[2];
  const float* wq    = (const float*)d_in[3];
  const float* wo    = (const float*)d_in[4];
  const float* ob    = (const float*)d_in[5];
  float* out = (float*)d_out;

  char* ws = (char*)d_ws;
  unsigned short* Xf  = (unsigned short*)(ws);                        // 4 MB frag-linear GN(x)
  unsigned short* Qf  = (unsigned short*)(ws + (4ull  << 20));        // 4 MB
  unsigned short* Kf  = (unsigned short*)(ws + (8ull  << 20));        // 4 MB
  unsigned short* Vf  = (unsigned short*)(ws + (12ull << 20));        // 4 MB
  unsigned short* wqf = (unsigned short*)(ws + (20ull << 20));        // 384 KB frag-linear
  unsigned short* wof = (unsigned short*)(ws + (20ull << 20) + (1u << 19)); // 128 KB
  float2* Sp          = (float2*)(ws + (20ull << 20) + (3u << 18));   // 2 KB
  float* Lp           = (float*)(ws + (21ull << 20));                 // 512 KB
  unsigned short* Opb = (unsigned short*)(ws + (22ull << 20));        // 16 MB

  k_prep<<<320, 256, 0, stream>>>(input, wq, wo, wqf, wof, Sp);
  k_gn_apply<<<dim3(64, 4, NBATCH), 256, 0, stream>>>(input, Sp, gnw, gnb, Xf);
  k_qkv<<<dim3(12, 64, NBATCH), 256, 0, stream>>>(wqf, Xf, Qf, Kf, Vf);
  k_attn<KSPLIT><<<dim3(32, NHEAD * NBATCH, KSPLIT), 256, 0, stream>>>(Qf, Kf, Vf, Opb, Lp);
  k_proj<<<dim3(256, NBATCH), 256, 0, stream>>>(wof, Opb, Lp, ob, input, out);
}